// Round 1
// baseline (1898.645 us; speedup 1.0000x reference)
//
#include <hip/hip_runtime.h>
#include <hip/hip_cooperative_groups.h>

namespace cg = cooperative_groups;

typedef unsigned short u16;
typedef unsigned int   u32;

typedef __bf16 bf16x8 __attribute__((ext_vector_type(8)));
typedef float  f32x4  __attribute__((ext_vector_type(4)));

#define NB 1023   // nodes per tree
#define HH 1024   // hidden

__device__ __forceinline__ float b2f(u16 x) { return __uint_as_float(((u32)x) << 16); }
__device__ __forceinline__ u16 f2b(float f) {
    u32 u = __float_as_uint(f);
    u += 0x7fffu + ((u >> 16) & 1u);   // RTNE
    return (u16)(u >> 16);
}
__device__ __forceinline__ float fast_tanh(float x) {
    float cx = fminf(fmaxf(x, -12.f), 12.f);
    float e = __expf(2.f * cx);
    return __fdividef(e - 1.f, e + 1.f);
}
__device__ __forceinline__ void async_copy16(const void* gptr, void* lptr) {
    __builtin_amdgcn_global_load_lds((__attribute__((address_space(1))) void*)gptr,
                                     (__attribute__((address_space(3))) void*)lptr,
                                     16, 0, 0);
}
__device__ __forceinline__ u16 loadAsBf16(const void* p, size_t idx, int isf32) {
    if (isf32) return f2b(((const float*)p)[idx]);
    return ((const u16*)p)[idx];
}

// per-block dtype detection: f32 mantissa low-halves have random exponents.
__device__ __forceinline__ int detect_local(const u32* __restrict__ w) {
    __shared__ int cnt;
    const int tid = threadIdx.x;
    if (tid == 0) cnt = 0;
    __syncthreads();
    u32 v = w[tid & 255];
    u32 lo = v & 0xFFFFu;
    u32 e = (lo >> 7) & 0xFFu;
    if ((lo != 0u) && (e < 60u || e > 140u)) atomicAdd(&cnt, 1);
    __syncthreads();
    return cnt >= 64;
}

// ---------------- unified preprocessing ----------------
__device__ void conv_range(const void* __restrict__ src, u16* __restrict__ dst,
                           int n, int tbase, int isf32) {
    const int i = ((int)blockIdx.x - tbase) * 256 + threadIdx.x;
    if (i < n) dst[i] = loadAsBf16(src, i, isf32);
}

__device__ void transpose_tile(const void* __restrict__ W, u16* __restrict__ Wt,
                               int Nw, int Kpad, int bx, int by, int isf32,
                               int ps0, int ps1, int ps2, int ps3,
                               int os0, int os1, int os2, int os3,
                               int ln0, int ln1, int ln2, int ln3)
{
    __shared__ u16 tile[32][33];
    const int tid = threadIdx.x;
    const int tx = tid & 31, ty = tid >> 5;
    #pragma unroll
    for (int i = 0; i < 4; ++i) {
        const int kp = by*32 + ty + i*8;
        const int n = bx*32 + tx;
        int ko = -1;
        if      (kp >= ps0 && kp < ps0 + ln0) ko = os0 + (kp - ps0);
        else if (kp >= ps1 && kp < ps1 + ln1) ko = os1 + (kp - ps1);
        else if (kp >= ps2 && kp < ps2 + ln2) ko = os2 + (kp - ps2);
        else if (kp >= ps3 && kp < ps3 + ln3) ko = os3 + (kp - ps3);
        u16 v = 0;
        if (ko >= 0) v = loadAsBf16(W, (size_t)ko * Nw + n, isf32);
        tile[ty + i*8][tx] = v;
    }
    __syncthreads();
    #pragma unroll
    for (int i = 0; i < 4; ++i) {
        const int n = bx*32 + ty + i*8;
        const int kp = by*32 + tx;
        Wt[(size_t)n * Kpad + kp] = tile[tx][ty + i*8];
    }
}

__global__ __launch_bounds__(256)
void preprocess(const u32* __restrict__ wembU,
                const void* __restrict__ semb,  const void* __restrict__ leafb,
                const void* __restrict__ compb, const void* __restrict__ grevb,
                const void* __restrict__ decb,  const void* __restrict__ clfb,
                const void* __restrict__ clfW,
                const void* __restrict__ leafW, const void* __restrict__ compW,
                const void* __restrict__ grevW, const void* __restrict__ decW,
                u16* __restrict__ sembP,  u16* __restrict__ leafbC,
                u16* __restrict__ compbC, u16* __restrict__ grevbC,
                u16* __restrict__ decbC,  u16* __restrict__ clfbC,
                u16* __restrict__ clfWC,
                u16* __restrict__ leafWt, u16* __restrict__ compWt,
                u16* __restrict__ grevWt, u16* __restrict__ decWt)
{
    const int isf32 = detect_local(wembU);
    const int bid = blockIdx.x;
    if (bid < 32) {                       // sembP: 128 rows, 50 -> 64 pad
        const int i = bid * 256 + threadIdx.x;   // 8192
        const int s = i >> 6, c = i & 63;
        sembP[i] = (c < 50) ? loadAsBf16(semb, s * 50 + c, isf32) : (u16)0;
    } else if (bid < 36)  conv_range(leafb, leafbC, 1024, 32, isf32);
    else if (bid < 40)  conv_range(compb, compbC, 1024, 36, isf32);
    else if (bid < 44)  conv_range(grevb, grevbC, 1024, 40, isf32);
    else if (bid < 52)  conv_range(decb,  decbC,  2048, 44, isf32);
    else if (bid < 53)  conv_range(clfb,  clfbC,  3,    52, isf32);
    else if (bid < 77)  conv_range(clfW,  clfWC,  6144, 53, isf32);
    else if (bid < 1165) {                // leafWt 32x34
        const int t = bid - 77;
        transpose_tile(leafW, leafWt, 1024, 1088, t & 31, t >> 5, isf32,
                       0,-1,-1,-1,  0,0,0,0,  1077,0,0,0);
    } else if (bid < 3277) {              // compWt 32x66
        const int t = bid - 1165;
        transpose_tile(compW, compWt, 1024, 2112, t & 31, t >> 5, isf32,
                       0,64,1088,-1,  0,50,1074,0,  50,1024,1024,0);
    } else if (bid < 4365) {              // grevWt 32x34
        const int t = bid - 3277;
        transpose_tile(grevW, grevWt, 1024, 1088, t & 31, t >> 5, isf32,
                       0,1024,-1,-1,  0,1024,0,0,  1024,50,0,0);
    } else {                              // decWt 64x68
        const int t = bid - 4365;
        transpose_tile(decW, decWt, 2048, 2176, t & 63, t >> 6, isf32,
                       0,64,128,1152,  0,50,100,1124,  50,50,1024,1024);
    }
}

// ---------------- leaf ctx (Kpad=1088): [word(1024) | onehot(3) | syn(pos)(50) | 0(11)]
__global__ __launch_bounds__(256)
void leaf_gather(const int* __restrict__ x, const int* __restrict__ cue,
                 const int* __restrict__ pos, const void* __restrict__ wemb,
                 const u16* __restrict__ sembP, u16* __restrict__ ctx)
{
    const int isf32 = detect_local((const u32*)wemb);
    const int m = blockIdx.x;           // 0..16383
    const int b = m >> 9, i = m & 511;
    const int node = 511 + i;
    const int s  = x[b*NB + node];
    const int cv = cue[b*NB + node];
    const int p  = pos[b*512 + i];
    u16* row = ctx + (size_t)m * 1088;
    u32* row32 = (u32*)row;
    const u16* sr = sembP + p * 64;
    const int tid = threadIdx.x;
    if (isf32) {
        const float2* wrf = ((const float2*)wemb) + (size_t)s * 512;
        for (int c = tid; c < 512; c += 256) {
            float2 t = wrf[c];
            row32[c] = (u32)f2b(t.x) | ((u32)f2b(t.y) << 16);
        }
    } else {
        const u32* wr = ((const u32*)wemb) + (size_t)s * 512;
        for (int c = tid; c < 512; c += 256) row32[c] = wr[c];
    }
    if (tid < 64) {
        const int c = tid;              // elem 1024+c
        u16 v;
        if (c < 3)       v = (c == cv) ? (u16)0x3F80 : (u16)0;
        else if (c < 53) v = sr[c - 3];
        else             v = 0;
        row[1024 + c] = v;
    }
}

// ---------------- fused gather+GEMM tile body, 2-phase prefetch over 32-wide chunks ----
// C[128x128 tile of M x N] = A[M x Kpad] * Bt[N x Kpad]^T + bias; A staged on the fly.
// AKIND 0: A = actx rows (leaf).             Kpad=1088
// AKIND 1: up level:   [semb(s)|up_l|up_r]   Kpad=2112 (64+1024+1024)
// AKIND 2: root:       [up0|semb(s)]         Kpad=1088 (1024+64)
// AKIND 3: down level: [sL|sR|down_n|up_n]   Kpad=2176 (64+64+1024+1024)
// MODE 0: store raw; 1: tanh; 2: tanh + child split (N=2048)
template<int AKIND, int MODE>
__device__ __forceinline__ void tile_body(
    u16* __restrict__ As, u16* __restrict__ Bs,
    const u16* __restrict__ Bt, const u16* __restrict__ bias,
    u16* __restrict__ dst, int M, int Kpad, int nodeBase, int lognn,
    int leafLvl,
    const u16* __restrict__ actx,
    const int* __restrict__ x, const int* __restrict__ pos,
    const u16* __restrict__ sembP,
    const u16* __restrict__ upB, const u16* __restrict__ downB,
    int bm, int bn)
{
    const int tid  = threadIdx.x;
    const int wave = tid >> 6;
    const int lane = tid & 63;
    const int wm = (wave & 1) << 6;
    const int wn = (wave >> 1) << 6;
    const int quad = lane >> 4;
    const int l16  = lane & 15;
    const int srow = lane >> 2;
    const int scol = (lane & 3) << 3;
    const int mask = (1 << lognn) - 1;

    // per-lane staging source pointers for its two A rows (mrow, mrow+64)
    const u16* p0[2]; const u16* p1[2]; const u16* p2[2]; const u16* p3[2];
    #pragma unroll
    for (int h = 0; h < 2; ++h) {
        const int mrow = bm + wave*16 + srow + h*64;
        const int mr = (mrow < M) ? mrow : 0;   // padded rows stage row 0, discarded at write
        if (AKIND == 0) {
            p0[h] = actx + (size_t)mr * Kpad + scol;
        } else if (AKIND == 1) {
            const int b_ = mr >> lognn, ii = mr & mask;
            const int node = nodeBase + ii;
            const int s = x[b_*NB + node];
            p0[h] = sembP + s*64 + scol;
            p1[h] = upB + (((size_t)(b_*NB + 2*node + 1)) << 10) + scol;
            p2[h] = upB + (((size_t)(b_*NB + 2*node + 2)) << 10) + scol;
        } else if (AKIND == 2) {
            p0[h] = upB + (((size_t)(mr*NB)) << 10) + scol;
            p1[h] = sembP + x[mr*NB]*64 + scol;
        } else {
            const int b_ = mr >> lognn, ii = mr & mask;
            const int node = nodeBase + ii;
            const int l = 2*node + 1, r = l + 1;
            int sli, sri;
            if (leafLvl) { sli = pos[b_*512 + (l-511)]; sri = pos[b_*512 + (r-511)]; }
            else         { sli = x[b_*NB + l]; sri = x[b_*NB + r]; }
            p0[h] = sembP + sli*64 + scol;
            p1[h] = sembP + sri*64 + scol;
            p2[h] = downB + (((size_t)(b_*NB + node)) << 10) + scol;
            p3[h] = upB   + (((size_t)(b_*NB + node)) << 10) + scol;
        }
    }

    const u16* gB0 = Bt + (size_t)(bn + wave*16 + srow) * Kpad + scol;
    const u16* gB1 = gB0 + (size_t)64 * Kpad;
    u16* lA0 = As + wave * 512;
    u16* lA1 = As + (wave + 4) * 512;
    u16* lB0 = Bs + wave * 512;
    u16* lB1 = Bs + (wave + 4) * 512;

    const u16* pa[4]; const u16* pb[4];
    #pragma unroll
    for (int i = 0; i < 4; ++i) pa[i] = As + (wm + i*16 + l16) * 32 + quad*8;
    #pragma unroll
    for (int j = 0; j < 4; ++j) pb[j] = Bs + (wn + j*16 + l16) * 32 + quad*8;

    f32x4 zero4 = {0.f, 0.f, 0.f, 0.f};
    f32x4 acc[4][4];
    #pragma unroll
    for (int i = 0; i < 4; ++i)
        #pragma unroll
        for (int j = 0; j < 4; ++j) acc[i][j] = zero4;

    // A-source for row h at K-offset k0 (k0 multiple of 32; every 32-chunk is
    // fully inside one segment since all segment lengths are multiples of 64)
    auto srcA = [&](int h, int k0) -> const u16* {
        if (AKIND == 0) return p0[h] + k0;
        if (AKIND == 1) return (k0 < 64) ? p0[h] + k0
                             : (k0 < 1088) ? p1[h] + (k0 - 64)
                             : p2[h] + (k0 - 1088);
        if (AKIND == 2) return (k0 < 1024) ? p0[h] + k0 : p1[h] + (k0 - 1024);
        return (k0 < 64)   ? p0[h] + k0
             : (k0 < 128)  ? p1[h] + (k0 - 64)
             : (k0 < 1152) ? p2[h] + (k0 - 128)
             : p3[h] + (k0 - 1152);
    };
    // stage chunk c (32 K-cols) into half (c&1)
    auto stage = [&](int c) {
        const int off = (c & 1) << 12;     // 4096 u16 = 8 KB half
        const int k0  = c << 5;
        async_copy16(srcA(0, k0), lA0 + off);
        async_copy16(srcA(1, k0), lA1 + off);
        async_copy16(gB0 + k0,    lB0 + off);
        async_copy16(gB1 + k0,    lB1 + off);
    };

    const int NT = Kpad >> 5;
    // 2-phase: prefetch chunk c+1 while computing chunk c; the single
    // __syncthreads() per chunk drains vmcnt(0) (copies of c+1) and
    // fences LDS reads of c before its buffer is re-staged.
    stage(0);
    __syncthreads();
    for (int c = 0; c < NT; ++c) {
        if (c + 1 < NT) stage(c + 1);
        const int off = (c & 1) << 12;
        bf16x8 a[4], b[4];
        #pragma unroll
        for (int i = 0; i < 4; ++i) a[i] = *(const bf16x8*)(pa[i] + off);
        #pragma unroll
        for (int j = 0; j < 4; ++j) b[j] = *(const bf16x8*)(pb[j] + off);
        #pragma unroll
        for (int i = 0; i < 4; ++i)
            #pragma unroll
            for (int j = 0; j < 4; ++j)
                acc[i][j] = __builtin_amdgcn_mfma_f32_16x16x32_bf16(a[i], b[j], acc[i][j], 0, 0, 0);
        __syncthreads();
    }

    #pragma unroll
    for (int i = 0; i < 4; ++i) {
        #pragma unroll
        for (int j = 0; j < 4; ++j) {
            const int gn = bn + wn + j*16 + l16;
            const float bv = b2f(bias[gn]);
            #pragma unroll
            for (int r = 0; r < 4; ++r) {
                const int gm = bm + wm + i*16 + quad*4 + r;
                if (gm < M) {
                    float v = acc[i][j][r] + bv;
                    if (MODE != 0) v = fast_tanh(v);
                    const int b_ = gm >> lognn;
                    const int ii = gm & mask;
                    const int node = nodeBase + ii;
                    size_t addr;
                    if (MODE == 2) {
                        const int child = 2*node + 1 + (gn >> 10);
                        addr = (((size_t)(b_*NB + child)) << 10) + (gn & 1023);
                    } else {
                        addr = (((size_t)(b_*NB + node)) << 10) + gn;
                    }
                    dst[addr] = f2b(v);
                }
            }
        }
    }
}

template<int AKIND, int MODE>
__global__ __launch_bounds__(256)
void gemm_fused(const u16* __restrict__ Bt, const u16* __restrict__ bias,
                u16* __restrict__ dst, int M, int Kpad, int nodeBase, int lognn,
                int leafLvl,
                const u16* __restrict__ actx,
                const int* __restrict__ x, const int* __restrict__ pos,
                const u16* __restrict__ sembP,
                const u16* __restrict__ upB, const u16* __restrict__ downB)
{
    __shared__ __align__(16) u16 As[8192];
    __shared__ __align__(16) u16 Bs[8192];
    // bijective XCD swizzle (m204): dispatch id bid runs on XCD bid&7; give each
    // XCD a contiguous chunk of the work-id space so neighbor tiles share L2.
    const int gx  = gridDim.x;
    const int nwg = gx * gridDim.y;
    int bid = blockIdx.y * gx + blockIdx.x;
    const int q = nwg >> 3, r = nwg & 7;
    const int xcd = bid & 7, lid = bid >> 3;
    bid = (xcd < r ? xcd * (q + 1) : r * (q + 1) + (xcd - r) * q) + lid;
    const int bx = bid % gx, by = bid / gx;
    tile_body<AKIND, MODE>(As, Bs, Bt, bias, dst, M, Kpad, nodeBase, lognn,
                           leafLvl, actx, x, pos, sembP, upB, downB,
                           by << 7, bx << 7);
}

// ---------------- cooperative chain: up lvl 7..0 -> root -> down lvl 0..6 ---------
// 256 blocks (1/CU guaranteed resident: 32 KB LDS, 256 thr). Levels needing more
// tiles (up8, down7, down8, leaf) stay as separate high-occupancy launches.
__global__ __launch_bounds__(256)
void tree_chain(const u16* __restrict__ compWt, const u16* __restrict__ compbC,
                const u16* __restrict__ grevWt, const u16* __restrict__ grevbC,
                const u16* __restrict__ decWt,  const u16* __restrict__ decbC,
                const int* __restrict__ x, const int* __restrict__ pos,
                const u16* __restrict__ sembP,
                u16* __restrict__ upB, u16* __restrict__ downB)
{
    __shared__ __align__(16) u16 As[8192];
    __shared__ __align__(16) u16 Bs[8192];
    cg::grid_group grid = cg::this_grid();
    const int bid = blockIdx.x;

    for (int lvl = 7; lvl >= 0; --lvl) {
        const int M = 32 << lvl;
        const int Mpad = M < 128 ? 128 : M;
        const int ntile = (Mpad >> 7) * 8;           // gx = 8 (N=1024)
        if (bid < ntile) {
            const int bx = bid & 7, by = bid >> 3;
            tile_body<1,1>(As, Bs, compWt, compbC, upB, M, 2112, (1 << lvl) - 1,
                           lvl, 0, nullptr, x, pos, sembP, upB, downB,
                           by << 7, bx << 7);
        }
        grid.sync();
    }
    if (bid < 8) {
        tile_body<2,1>(As, Bs, grevWt, grevbC, downB, 32, 1088, 0, 0, 0,
                       nullptr, x, pos, sembP, upB, downB, 0, bid << 7);
    }
    grid.sync();
    for (int lvl = 0; lvl <= 6; ++lvl) {
        const int M = 32 << lvl;
        const int Mpad = M < 128 ? 128 : M;
        const int ntile = (Mpad >> 7) * 16;          // gx = 16 (N=2048)
        if (bid < ntile) {
            const int bx = bid & 15, by = bid >> 4;
            tile_body<3,2>(As, Bs, decWt, decbC, downB, M, 2176, (1 << lvl) - 1,
                           lvl, 0, nullptr, x, pos, sembP, upB, downB,
                           by << 7, bx << 7);
        }
        grid.sync();
    }
}

// ---------------- classifier: out[b,n,c] = tanh([down|up] . clfW[:,c] + clfb[c]) ----
__global__ __launch_bounds__(256)
void classifier_kernel(const u16* __restrict__ down, const u16* __restrict__ up,
                       const u16* __restrict__ clfW, const u16* __restrict__ clfb,
                       void* __restrict__ outp, const u32* __restrict__ wembU)
{
    __shared__ float wls[3][2048];
    const int isf32 = detect_local(wembU);
    const int tid = threadIdx.x;
    for (int idx = tid; idx < 6144; idx += 256) {
        const int c = idx >> 11, k = idx & 2047;
        wls[c][k] = b2f(clfW[k*3 + c]);
    }
    __syncthreads();
    const int wave = tid >> 6, lane = tid & 63;
    const float b0 = b2f(clfb[0]), b1 = b2f(clfb[1]), b2v = b2f(clfb[2]);
    const int base = blockIdx.x * 32;
    for (int rr = 0; rr < 8; ++rr) {
        const int row = base + rr*4 + wave;     // row = b*NB + node
        const u32* dn = (const u32*)(down + ((size_t)row << 10));
        const u32* un = (const u32*)(up   + ((size_t)row << 10));
        float a0 = 0.f, a1 = 0.f, a2 = 0.f;
        #pragma unroll
        for (int t = 0; t < 8; ++t) {
            const int j = t*64 + lane;
            const u32 dp = dn[j], uu = un[j];
            const int k = j*2;
            const float d0 = __uint_as_float(dp << 16);
            const float d1 = __uint_as_float(dp & 0xffff0000u);
            const float u0 = __uint_as_float(uu << 16);
            const float u1 = __uint_as_float(uu & 0xffff0000u);
            a0 += d0*wls[0][k] + d1*wls[0][k+1] + u0*wls[0][1024+k] + u1*wls[0][1025+k];
            a1 += d0*wls[1][k] + d1*wls[1][k+1] + u0*wls[1][1024+k] + u1*wls[1][1025+k];
            a2 += d0*wls[2][k] + d1*wls[2][k+1] + u0*wls[2][1024+k] + u1*wls[2][1025+k];
        }
        #pragma unroll
        for (int off = 32; off; off >>= 1) {
            a0 += __shfl_down(a0, off);
            a1 += __shfl_down(a1, off);
            a2 += __shfl_down(a2, off);
        }
        if (lane == 0) {
            const float v0 = fast_tanh(a0 + b0);
            const float v1 = fast_tanh(a1 + b1);
            const float v2 = fast_tanh(a2 + b2v);
            if (isf32) {
                float* o = (float*)outp + (size_t)row * 3;
                o[0] = v0; o[1] = v1; o[2] = v2;
            } else {
                u16* o = (u16*)outp + (size_t)row * 3;
                o[0] = f2b(v0); o[1] = f2b(v1); o[2] = f2b(v2);
            }
        }
    }
}

extern "C" void kernel_launch(void* const* d_in, const int* in_sizes, int n_in,
                              void* d_out, int out_size, void* d_ws, size_t ws_size,
                              hipStream_t stream)
{
    (void)in_sizes; (void)n_in; (void)out_size; (void)ws_size;
    const int* x    = (const int*)d_in[0];
    const int* cue  = (const int*)d_in[2];
    const int* pos  = (const int*)d_in[4];
    const void* wemb  = d_in[6];
    const void* semb  = d_in[7];
    const void* leafW = d_in[8];
    const void* leafb = d_in[9];
    const void* compW = d_in[10];
    const void* compb = d_in[11];
    const void* grevW = d_in[12];
    const void* grevb = d_in[13];
    const void* decW  = d_in[14];
    const void* decb  = d_in[15];
    const void* clfW  = d_in[16];
    const void* clfb  = d_in[17];

    char* ws = (char*)d_ws;
    u16* up_buf   = (u16*)(ws + 0);            // 67043328
    u16* down_buf = (u16*)(ws + 67043328);     // 67043328
    u16* ctx      = (u16*)(ws + 134086656);    // 35651584 (leaf only)
    u16* leafWt   = (u16*)(ws + 169738240);    // 1024x1088
    u16* compWt   = (u16*)(ws + 171966464);    // 1024x2112
    u16* grevWt   = (u16*)(ws + 176291840);    // 1024x1088
    u16* decWt    = (u16*)(ws + 178520064);    // 2048x2176
    u16* sembP    = (u16*)(ws + 187432960);    // 128x64
    u16* leafbC   = (u16*)(ws + 187449344);
    u16* compbC   = (u16*)(ws + 187451392);
    u16* grevbC   = (u16*)(ws + 187453440);
    u16* decbC    = (u16*)(ws + 187455488);
    u16* clfbC    = (u16*)(ws + 187459584);
    u16* clfWC    = (u16*)(ws + 187459600);

    preprocess<<<8717, 256, 0, stream>>>((const u32*)wemb,
        semb, leafb, compb, grevb, decb, clfb, clfW,
        leafW, compW, grevW, decW,
        sembP, leafbC, compbC, grevbC, decbC, clfbC, clfWC,
        leafWt, compWt, grevWt, decWt);

    // leaves -> up[511..1022]
    leaf_gather<<<16384, 256, 0, stream>>>(x, cue, pos, wemb, sembP, ctx);
    gemm_fused<0,0><<<dim3(8, 128), 256, 0, stream>>>(leafWt, leafbC, up_buf,
        16384, 1088, 511, 9, 0, ctx, x, pos, sembP, up_buf, down_buf);
    // up lvl 8 (big, 512 tiles)
    gemm_fused<1,1><<<dim3(8, 64), 256, 0, stream>>>(compWt, compbC, up_buf,
        8192, 2112, 255, 8, 0, nullptr, x, pos, sembP, up_buf, down_buf);

    // fused chain: up 7..0 -> root -> down 0..6 (one cooperative dispatch)
    const u16* compWt_c = compWt; const u16* compbC_c = compbC;
    const u16* grevWt_c = grevWt; const u16* grevbC_c = grevbC;
    const u16* decWt_c  = decWt;  const u16* decbC_c  = decbC;
    const u16* sembP_c  = sembP;
    void* args[] = {(void*)&compWt_c, (void*)&compbC_c, (void*)&grevWt_c,
                    (void*)&grevbC_c, (void*)&decWt_c,  (void*)&decbC_c,
                    (void*)&x, (void*)&pos, (void*)&sembP_c,
                    (void*)&up_buf, (void*)&down_buf};
    hipError_t ce = hipLaunchCooperativeKernel((const void*)tree_chain,
                                               dim3(256), dim3(256), args, 0, stream);
    if (ce != hipSuccess) {
        (void)hipGetLastError();
        // fallback: per-level launches (old path)
        for (int lvl = 7; lvl >= 0; --lvl) {
            const int M = 32 << lvl;
            const int Mpad = M < 128 ? 128 : M;
            const int first = (1 << lvl) - 1;
            gemm_fused<1,1><<<dim3(8, Mpad >> 7), 256, 0, stream>>>(compWt, compbC, up_buf,
                M, 2112, first, lvl, 0, nullptr, x, pos, sembP, up_buf, down_buf);
        }
        gemm_fused<2,1><<<dim3(8, 1), 256, 0, stream>>>(grevWt, grevbC, down_buf,
            32, 1088, 0, 0, 0, nullptr, x, pos, sembP, up_buf, down_buf);
        for (int lvl = 0; lvl <= 6; ++lvl) {
            const int M = 32 << lvl;
            const int Mpad = M < 128 ? 128 : M;
            const int first = (1 << lvl) - 1;
            gemm_fused<3,2><<<dim3(16, Mpad >> 7), 256, 0, stream>>>(decWt, decbC, down_buf,
                M, 2176, first, lvl, 0, nullptr, x, pos, sembP, up_buf, down_buf);
        }
    }

    // down lvl 7, 8 (big)
    gemm_fused<3,2><<<dim3(16, 32), 256, 0, stream>>>(decWt, decbC, down_buf,
        4096, 2176, 127, 7, 0, nullptr, x, pos, sembP, up_buf, down_buf);
    gemm_fused<3,2><<<dim3(16, 64), 256, 0, stream>>>(decWt, decbC, down_buf,
        8192, 2176, 255, 8, 1, nullptr, x, pos, sembP, up_buf, down_buf);

    // classifier
    classifier_kernel<<<1023, 256, 0, stream>>>(down_buf, up_buf, clfWC, clfbC,
                                                d_out, (const u32*)wemb);
}

// Round 2
// 1633.022 us; speedup vs baseline: 1.1627x; 1.1627x over previous
//
#include <hip/hip_runtime.h>

typedef unsigned short u16;
typedef unsigned int   u32;

typedef __bf16 bf16x8 __attribute__((ext_vector_type(8)));
typedef float  f32x4  __attribute__((ext_vector_type(4)));

#define NB 1023   // nodes per tree
#define HH 1024   // hidden

__device__ __forceinline__ float b2f(u16 x) { return __uint_as_float(((u32)x) << 16); }
__device__ __forceinline__ u16 f2b(float f) {
    u32 u = __float_as_uint(f);
    u += 0x7fffu + ((u >> 16) & 1u);   // RTNE
    return (u16)(u >> 16);
}
__device__ __forceinline__ float fast_tanh(float x) {
    float cx = fminf(fmaxf(x, -12.f), 12.f);
    float e = __expf(2.f * cx);
    return __fdividef(e - 1.f, e + 1.f);
}
__device__ __forceinline__ void async_copy16(const void* gptr, void* lptr) {
    __builtin_amdgcn_global_load_lds((__attribute__((address_space(1))) void*)gptr,
                                     (__attribute__((address_space(3))) void*)lptr,
                                     16, 0, 0);
}
__device__ __forceinline__ u16 loadAsBf16(const void* p, size_t idx, int isf32) {
    if (isf32) return f2b(((const float*)p)[idx]);
    return ((const u16*)p)[idx];
}

// per-block dtype detection: f32 mantissa low-halves have random exponents.
__device__ __forceinline__ int detect_local(const u32* __restrict__ w) {
    __shared__ int cnt;
    const int tid = threadIdx.x;
    if (tid == 0) cnt = 0;
    __syncthreads();
    u32 v = w[tid & 255];
    u32 lo = v & 0xFFFFu;
    u32 e = (lo >> 7) & 0xFFu;
    if ((lo != 0u) && (e < 60u || e > 140u)) atomicAdd(&cnt, 1);
    __syncthreads();
    return cnt >= 64;
}

// ---------------- hand-rolled grid barrier (sense-reversing, agent scope) ----------
// bar[0] = arrival counter, bar[1] = generation. Initialized by preprocess each run.
// Requires all blocks resident: 256 blocks, 64 KB LDS -> >=2 blocks/CU capacity, OK.
__device__ __forceinline__ void grid_bar(u32* bar, int nb) {
    __syncthreads();
    if (threadIdx.x == 0) {
        __threadfence();   // release: writeback L2 so other XCDs see our stores
        u32 g = __hip_atomic_load(&bar[1], __ATOMIC_RELAXED, __HIP_MEMORY_SCOPE_AGENT);
        u32 v = __hip_atomic_fetch_add(&bar[0], 1u, __ATOMIC_RELAXED, __HIP_MEMORY_SCOPE_AGENT);
        if (v == (u32)nb - 1u) {
            __hip_atomic_store(&bar[0], 0u, __ATOMIC_RELAXED, __HIP_MEMORY_SCOPE_AGENT);
            __hip_atomic_store(&bar[1], g + 1u, __ATOMIC_RELEASE, __HIP_MEMORY_SCOPE_AGENT);
        } else {
            while (__hip_atomic_load(&bar[1], __ATOMIC_RELAXED, __HIP_MEMORY_SCOPE_AGENT) == g) {
                __builtin_amdgcn_s_sleep(2);
            }
        }
        __threadfence();   // acquire: invalidate L1/L2 so we see producers' stores
    }
    __syncthreads();
}

// ---------------- unified preprocessing ----------------
__device__ void conv_range(const void* __restrict__ src, u16* __restrict__ dst,
                           int n, int tbase, int isf32) {
    const int i = ((int)blockIdx.x - tbase) * 256 + threadIdx.x;
    if (i < n) dst[i] = loadAsBf16(src, i, isf32);
}

__device__ void transpose_tile(const void* __restrict__ W, u16* __restrict__ Wt,
                               int Nw, int Kpad, int bx, int by, int isf32,
                               int ps0, int ps1, int ps2, int ps3,
                               int os0, int os1, int os2, int os3,
                               int ln0, int ln1, int ln2, int ln3)
{
    __shared__ u16 tile[32][33];
    const int tid = threadIdx.x;
    const int tx = tid & 31, ty = tid >> 5;
    #pragma unroll
    for (int i = 0; i < 4; ++i) {
        const int kp = by*32 + ty + i*8;
        const int n = bx*32 + tx;
        int ko = -1;
        if      (kp >= ps0 && kp < ps0 + ln0) ko = os0 + (kp - ps0);
        else if (kp >= ps1 && kp < ps1 + ln1) ko = os1 + (kp - ps1);
        else if (kp >= ps2 && kp < ps2 + ln2) ko = os2 + (kp - ps2);
        else if (kp >= ps3 && kp < ps3 + ln3) ko = os3 + (kp - ps3);
        u16 v = 0;
        if (ko >= 0) v = loadAsBf16(W, (size_t)ko * Nw + n, isf32);
        tile[ty + i*8][tx] = v;
    }
    __syncthreads();
    #pragma unroll
    for (int i = 0; i < 4; ++i) {
        const int n = bx*32 + ty + i*8;
        const int kp = by*32 + tx;
        Wt[(size_t)n * Kpad + kp] = tile[tx][ty + i*8];
    }
}

__global__ __launch_bounds__(256)
void preprocess(const u32* __restrict__ wembU,
                const void* __restrict__ semb,  const void* __restrict__ leafb,
                const void* __restrict__ compb, const void* __restrict__ grevb,
                const void* __restrict__ decb,  const void* __restrict__ clfb,
                const void* __restrict__ clfW,
                const void* __restrict__ leafW, const void* __restrict__ compW,
                const void* __restrict__ grevW, const void* __restrict__ decW,
                u16* __restrict__ sembP,  u16* __restrict__ leafbC,
                u16* __restrict__ compbC, u16* __restrict__ grevbC,
                u16* __restrict__ decbC,  u16* __restrict__ clfbC,
                u16* __restrict__ clfWC,
                u16* __restrict__ leafWt, u16* __restrict__ compWt,
                u16* __restrict__ grevWt, u16* __restrict__ decWt,
                u32* __restrict__ bar)
{
    const int isf32 = detect_local(wembU);
    const int bid = blockIdx.x;
    if (bid == 0 && threadIdx.x == 0) { bar[0] = 0; bar[1] = 0; }
    if (bid < 32) {                       // sembP: 128 rows, 50 -> 64 pad
        const int i = bid * 256 + threadIdx.x;   // 8192
        const int s = i >> 6, c = i & 63;
        sembP[i] = (c < 50) ? loadAsBf16(semb, s * 50 + c, isf32) : (u16)0;
    } else if (bid < 36)  conv_range(leafb, leafbC, 1024, 32, isf32);
    else if (bid < 40)  conv_range(compb, compbC, 1024, 36, isf32);
    else if (bid < 44)  conv_range(grevb, grevbC, 1024, 40, isf32);
    else if (bid < 52)  conv_range(decb,  decbC,  2048, 44, isf32);
    else if (bid < 53)  conv_range(clfb,  clfbC,  3,    52, isf32);
    else if (bid < 77)  conv_range(clfW,  clfWC,  6144, 53, isf32);
    else if (bid < 1165) {                // leafWt 32x34
        const int t = bid - 77;
        transpose_tile(leafW, leafWt, 1024, 1088, t & 31, t >> 5, isf32,
                       0,-1,-1,-1,  0,0,0,0,  1077,0,0,0);
    } else if (bid < 3277) {              // compWt 32x66
        const int t = bid - 1165;
        transpose_tile(compW, compWt, 1024, 2112, t & 31, t >> 5, isf32,
                       0,64,1088,-1,  0,50,1074,0,  50,1024,1024,0);
    } else if (bid < 4365) {              // grevWt 32x34
        const int t = bid - 3277;
        transpose_tile(grevW, grevWt, 1024, 1088, t & 31, t >> 5, isf32,
                       0,1024,-1,-1,  0,1024,0,0,  1024,50,0,0);
    } else {                              // decWt 64x68
        const int t = bid - 4365;
        transpose_tile(decW, decWt, 2048, 2176, t & 63, t >> 6, isf32,
                       0,64,128,1152,  0,50,100,1124,  50,50,1024,1024);
    }
}

// ---------------- leaf ctx (Kpad=1088): [word(1024) | onehot(3) | syn(pos)(50) | 0(11)]
__global__ __launch_bounds__(256)
void leaf_gather(const int* __restrict__ x, const int* __restrict__ cue,
                 const int* __restrict__ pos, const void* __restrict__ wemb,
                 const u16* __restrict__ sembP, u16* __restrict__ ctx)
{
    const int isf32 = detect_local((const u32*)wemb);
    const int m = blockIdx.x;           // 0..16383
    const int b = m >> 9, i = m & 511;
    const int node = 511 + i;
    const int s  = x[b*NB + node];
    const int cv = cue[b*NB + node];
    const int p  = pos[b*512 + i];
    u16* row = ctx + (size_t)m * 1088;
    u32* row32 = (u32*)row;
    const u16* sr = sembP + p * 64;
    const int tid = threadIdx.x;
    if (isf32) {
        const float2* wrf = ((const float2*)wemb) + (size_t)s * 512;
        for (int c = tid; c < 512; c += 256) {
            float2 t = wrf[c];
            row32[c] = (u32)f2b(t.x) | ((u32)f2b(t.y) << 16);
        }
    } else {
        const u32* wr = ((const u32*)wemb) + (size_t)s * 512;
        for (int c = tid; c < 512; c += 256) row32[c] = wr[c];
    }
    if (tid < 64) {
        const int c = tid;              // elem 1024+c
        u16 v;
        if (c < 3)       v = (c == cv) ? (u16)0x3F80 : (u16)0;
        else if (c < 53) v = sr[c - 3];
        else             v = 0;
        row[1024 + c] = v;
    }
}

// ---------------- fused gather+GEMM tile body (shallow, __syncthreads 2-phase) ----
// C[128x128 tile of M x N] = A[M x Kpad] * Bt[N x Kpad]^T + bias; A staged on the fly.
// AKIND 0: A = actx rows (leaf).             Kpad=1088
// AKIND 1: up level:   [semb(s)|up_l|up_r]   Kpad=2112 (64+1024+1024)
// AKIND 2: root:       [up0|semb(s)]         Kpad=1088 (1024+64)
// AKIND 3: down level: [sL|sR|down_n|up_n]   Kpad=2176 (64+64+1024+1024)
// MODE 0: store raw; 1: tanh; 2: tanh + child split (N=2048)
template<int AKIND, int MODE>
__device__ __forceinline__ void tile_body(
    u16* __restrict__ As, u16* __restrict__ Bs,
    const u16* __restrict__ Bt, const u16* __restrict__ bias,
    u16* __restrict__ dst, int M, int Kpad, int nodeBase, int lognn,
    int leafLvl,
    const u16* __restrict__ actx,
    const int* __restrict__ x, const int* __restrict__ pos,
    const u16* __restrict__ sembP,
    const u16* __restrict__ upB, const u16* __restrict__ downB,
    int bm, int bn)
{
    const int tid  = threadIdx.x;
    const int wave = tid >> 6;
    const int lane = tid & 63;
    const int wm = (wave & 1) << 6;
    const int wn = (wave >> 1) << 6;
    const int quad = lane >> 4;
    const int l16  = lane & 15;
    const int srow = lane >> 2;
    const int scol = (lane & 3) << 3;
    const int mask = (1 << lognn) - 1;

    // per-lane staging source pointers for its two A rows (mrow, mrow+64)
    const u16* p0[2]; const u16* p1[2]; const u16* p2[2]; const u16* p3[2];
    #pragma unroll
    for (int h = 0; h < 2; ++h) {
        const int mrow = bm + wave*16 + srow + h*64;
        const int mr = (mrow < M) ? mrow : 0;   // padded rows stage row 0, discarded at write
        if (AKIND == 0) {
            p0[h] = actx + (size_t)mr * Kpad + scol;
        } else if (AKIND == 1) {
            const int b_ = mr >> lognn, ii = mr & mask;
            const int node = nodeBase + ii;
            const int s = x[b_*NB + node];
            p0[h] = sembP + s*64 + scol;
            p1[h] = upB + (((size_t)(b_*NB + 2*node + 1)) << 10) + scol;
            p2[h] = upB + (((size_t)(b_*NB + 2*node + 2)) << 10) + scol;
        } else if (AKIND == 2) {
            p0[h] = upB + (((size_t)(mr*NB)) << 10) + scol;
            p1[h] = sembP + x[mr*NB]*64 + scol;
        } else {
            const int b_ = mr >> lognn, ii = mr & mask;
            const int node = nodeBase + ii;
            const int l = 2*node + 1, r = l + 1;
            int sli, sri;
            if (leafLvl) { sli = pos[b_*512 + (l-511)]; sri = pos[b_*512 + (r-511)]; }
            else         { sli = x[b_*NB + l]; sri = x[b_*NB + r]; }
            p0[h] = sembP + sli*64 + scol;
            p1[h] = sembP + sri*64 + scol;
            p2[h] = downB + (((size_t)(b_*NB + node)) << 10) + scol;
            p3[h] = upB   + (((size_t)(b_*NB + node)) << 10) + scol;
        }
    }

    const u16* gB0 = Bt + (size_t)(bn + wave*16 + srow) * Kpad + scol;
    const u16* gB1 = gB0 + (size_t)64 * Kpad;
    u16* lA0 = As + wave * 512;
    u16* lA1 = As + (wave + 4) * 512;
    u16* lB0 = Bs + wave * 512;
    u16* lB1 = Bs + (wave + 4) * 512;

    const u16* pa[4]; const u16* pb[4];
    #pragma unroll
    for (int i = 0; i < 4; ++i) pa[i] = As + (wm + i*16 + l16) * 32 + quad*8;
    #pragma unroll
    for (int j = 0; j < 4; ++j) pb[j] = Bs + (wn + j*16 + l16) * 32 + quad*8;

    f32x4 zero4 = {0.f, 0.f, 0.f, 0.f};
    f32x4 acc[4][4];
    #pragma unroll
    for (int i = 0; i < 4; ++i)
        #pragma unroll
        for (int j = 0; j < 4; ++j) acc[i][j] = zero4;

    auto srcA = [&](int h, int k0) -> const u16* {
        if (AKIND == 0) return p0[h] + k0;
        if (AKIND == 1) return (k0 < 64) ? p0[h] + k0
                             : (k0 < 1088) ? p1[h] + (k0 - 64)
                             : p2[h] + (k0 - 1088);
        if (AKIND == 2) return (k0 < 1024) ? p0[h] + k0 : p1[h] + (k0 - 1024);
        return (k0 < 64)   ? p0[h] + k0
             : (k0 < 128)  ? p1[h] + (k0 - 64)
             : (k0 < 1152) ? p2[h] + (k0 - 128)
             : p3[h] + (k0 - 1152);
    };
    auto stage = [&](int c) {
        const int off = (c & 1) << 12;     // 4096 u16 = 8 KB half
        const int k0  = c << 5;
        async_copy16(srcA(0, k0), lA0 + off);
        async_copy16(srcA(1, k0), lA1 + off);
        async_copy16(gB0 + k0,    lB0 + off);
        async_copy16(gB1 + k0,    lB1 + off);
    };

    const int NT = Kpad >> 5;
    stage(0);
    __syncthreads();
    for (int c = 0; c < NT; ++c) {
        if (c + 1 < NT) stage(c + 1);
        const int off = (c & 1) << 12;
        bf16x8 a[4], b[4];
        #pragma unroll
        for (int i = 0; i < 4; ++i) a[i] = *(const bf16x8*)(pa[i] + off);
        #pragma unroll
        for (int j = 0; j < 4; ++j) b[j] = *(const bf16x8*)(pb[j] + off);
        #pragma unroll
        for (int i = 0; i < 4; ++i)
            #pragma unroll
            for (int j = 0; j < 4; ++j)
                acc[i][j] = __builtin_amdgcn_mfma_f32_16x16x32_bf16(a[i], b[j], acc[i][j], 0, 0, 0);
        __syncthreads();
    }

    #pragma unroll
    for (int i = 0; i < 4; ++i) {
        #pragma unroll
        for (int j = 0; j < 4; ++j) {
            const int gn = bn + wn + j*16 + l16;
            const float bv = b2f(bias[gn]);
            #pragma unroll
            for (int r = 0; r < 4; ++r) {
                const int gm = bm + wm + i*16 + quad*4 + r;
                if (gm < M) {
                    float v = acc[i][j][r] + bv;
                    if (MODE != 0) v = fast_tanh(v);
                    const int b_ = gm >> lognn;
                    const int ii = gm & mask;
                    const int node = nodeBase + ii;
                    size_t addr;
                    if (MODE == 2) {
                        const int child = 2*node + 1 + (gn >> 10);
                        addr = (((size_t)(b_*NB + child)) << 10) + (gn & 1023);
                    } else {
                        addr = (((size_t)(b_*NB + node)) << 10) + gn;
                    }
                    dst[addr] = f2b(v);
                }
            }
        }
    }
}

// ---------------- deep-pipelined tile body (D=4, counted vmcnt, raw barriers) ------
// Used only inside tree_chain (1 block/CU, latency-bound). 4 LDS slots per operand.
// Per chunk: wait vmcnt so chunk c (issued 3 chunks ago) is done -> barrier ->
// ds_read+MFMA -> barrier (all waves done reading slot) -> stage chunk c+3.
template<int AKIND, int MODE>
__device__ __forceinline__ void tile_body_deep(
    u16* __restrict__ As, u16* __restrict__ Bs,
    const u16* __restrict__ Bt, const u16* __restrict__ bias,
    u16* __restrict__ dst, int M, int Kpad, int nodeBase, int lognn,
    const int* __restrict__ x, const int* __restrict__ pos,
    const u16* __restrict__ sembP,
    const u16* __restrict__ upB, const u16* __restrict__ downB,
    int bm, int bn)
{
    const int tid  = threadIdx.x;
    const int wave = tid >> 6;
    const int lane = tid & 63;
    const int wm = (wave & 1) << 6;
    const int wn = (wave >> 1) << 6;
    const int quad = lane >> 4;
    const int l16  = lane & 15;
    const int srow = lane >> 2;
    const int scol = (lane & 3) << 3;
    const int mask = (1 << lognn) - 1;

    const u16* p0[2]; const u16* p1[2]; const u16* p2[2]; const u16* p3[2];
    #pragma unroll
    for (int h = 0; h < 2; ++h) {
        const int mrow = bm + wave*16 + srow + h*64;
        const int mr = (mrow < M) ? mrow : 0;
        if (AKIND == 1) {
            const int b_ = mr >> lognn, ii = mr & mask;
            const int node = nodeBase + ii;
            const int s = x[b_*NB + node];
            p0[h] = sembP + s*64 + scol;
            p1[h] = upB + (((size_t)(b_*NB + 2*node + 1)) << 10) + scol;
            p2[h] = upB + (((size_t)(b_*NB + 2*node + 2)) << 10) + scol;
        } else if (AKIND == 2) {
            p0[h] = upB + (((size_t)(mr*NB)) << 10) + scol;
            p1[h] = sembP + x[mr*NB]*64 + scol;
        } else {
            const int b_ = mr >> lognn, ii = mr & mask;
            const int node = nodeBase + ii;
            const int l = 2*node + 1, r = l + 1;
            const int sli = x[b_*NB + l], sri = x[b_*NB + r];
            p0[h] = sembP + sli*64 + scol;
            p1[h] = sembP + sri*64 + scol;
            p2[h] = downB + (((size_t)(b_*NB + node)) << 10) + scol;
            p3[h] = upB   + (((size_t)(b_*NB + node)) << 10) + scol;
        }
    }

    const u16* gB0 = Bt + (size_t)(bn + wave*16 + srow) * Kpad + scol;
    const u16* gB1 = gB0 + (size_t)64 * Kpad;
    u16* lA0 = As + wave * 512;
    u16* lA1 = As + (wave + 4) * 512;
    u16* lB0 = Bs + wave * 512;
    u16* lB1 = Bs + (wave + 4) * 512;

    const u16* pa[4]; const u16* pb[4];
    #pragma unroll
    for (int i = 0; i < 4; ++i) pa[i] = As + (wm + i*16 + l16) * 32 + quad*8;
    #pragma unroll
    for (int j = 0; j < 4; ++j) pb[j] = Bs + (wn + j*16 + l16) * 32 + quad*8;

    f32x4 zero4 = {0.f, 0.f, 0.f, 0.f};
    f32x4 acc[4][4];
    #pragma unroll
    for (int i = 0; i < 4; ++i)
        #pragma unroll
        for (int j = 0; j < 4; ++j) acc[i][j] = zero4;

    auto srcA = [&](int h, int k0) -> const u16* {
        if (AKIND == 1) return (k0 < 64) ? p0[h] + k0
                             : (k0 < 1088) ? p1[h] + (k0 - 64)
                             : p2[h] + (k0 - 1088);
        if (AKIND == 2) return (k0 < 1024) ? p0[h] + k0 : p1[h] + (k0 - 1024);
        return (k0 < 64)   ? p0[h] + k0
             : (k0 < 128)  ? p1[h] + (k0 - 64)
             : (k0 < 1152) ? p2[h] + (k0 - 128)
             : p3[h] + (k0 - 1152);
    };
    auto stage = [&](int c) {
        const int off = (c & 3) << 12;     // 4 slots x 4096 u16
        const int k0  = c << 5;
        async_copy16(srcA(0, k0), lA0 + off);
        async_copy16(srcA(1, k0), lA1 + off);
        async_copy16(gB0 + k0,    lB0 + off);
        async_copy16(gB1 + k0,    lB1 + off);
    };

    const int NT = Kpad >> 5;              // >= 34 for all chain shapes
    stage(0); stage(1); stage(2);          // 3 stages in flight (12 vmem/wave)
    for (int c = 0; c < NT; ++c) {
        // wait until my chunk-c loads done (leave newer stages in flight)
        if (c + 2 < NT)      asm volatile("s_waitcnt vmcnt(8)" ::: "memory");
        else if (c + 1 < NT) asm volatile("s_waitcnt vmcnt(4)" ::: "memory");
        else                 asm volatile("s_waitcnt vmcnt(0)" ::: "memory");
        asm volatile("s_barrier" ::: "memory");   // all waves' chunk-c loads landed
        const int off = (c & 3) << 12;
        bf16x8 a[4], b[4];
        #pragma unroll
        for (int i = 0; i < 4; ++i) a[i] = *(const bf16x8*)(pa[i] + off);
        #pragma unroll
        for (int j = 0; j < 4; ++j) b[j] = *(const bf16x8*)(pb[j] + off);
        #pragma unroll
        for (int i = 0; i < 4; ++i)
            #pragma unroll
            for (int j = 0; j < 4; ++j)
                acc[i][j] = __builtin_amdgcn_mfma_f32_16x16x32_bf16(a[i], b[j], acc[i][j], 0, 0, 0);
        asm volatile("s_barrier" ::: "memory");   // all waves done reading slot c%4
        if (c + 3 < NT) stage(c + 3);             // overwrites slot (c-1)%4: safe
    }

    #pragma unroll
    for (int i = 0; i < 4; ++i) {
        #pragma unroll
        for (int j = 0; j < 4; ++j) {
            const int gn = bn + wn + j*16 + l16;
            const float bv = b2f(bias[gn]);
            #pragma unroll
            for (int r = 0; r < 4; ++r) {
                const int gm = bm + wm + i*16 + quad*4 + r;
                if (gm < M) {
                    float v = acc[i][j][r] + bv;
                    v = fast_tanh(v);
                    const int b_ = gm >> lognn;
                    const int ii = gm & mask;
                    const int node = nodeBase + ii;
                    size_t addr;
                    if (MODE == 2) {
                        const int child = 2*node + 1 + (gn >> 10);
                        addr = (((size_t)(b_*NB + child)) << 10) + (gn & 1023);
                    } else {
                        addr = (((size_t)(b_*NB + node)) << 10) + gn;
                    }
                    dst[addr] = f2b(v);
                }
            }
        }
    }
}

template<int AKIND, int MODE>
__global__ __launch_bounds__(256)
void gemm_fused(const u16* __restrict__ Bt, const u16* __restrict__ bias,
                u16* __restrict__ dst, int M, int Kpad, int nodeBase, int lognn,
                int leafLvl,
                const u16* __restrict__ actx,
                const int* __restrict__ x, const int* __restrict__ pos,
                const u16* __restrict__ sembP,
                const u16* __restrict__ upB, const u16* __restrict__ downB)
{
    __shared__ __align__(16) u16 As[8192];
    __shared__ __align__(16) u16 Bs[8192];
    // bijective XCD swizzle (m204)
    const int gx  = gridDim.x;
    const int nwg = gx * gridDim.y;
    int bid = blockIdx.y * gx + blockIdx.x;
    const int q = nwg >> 3, r = nwg & 7;
    const int xcd = bid & 7, lid = bid >> 3;
    bid = (xcd < r ? xcd * (q + 1) : r * (q + 1) + (xcd - r) * q) + lid;
    const int bx = bid % gx, by = bid / gx;
    tile_body<AKIND, MODE>(As, Bs, Bt, bias, dst, M, Kpad, nodeBase, lognn,
                           leafLvl, actx, x, pos, sembP, upB, downB,
                           by << 7, bx << 7);
}

// ---------------- chained small levels: up 7..0 -> root -> down 0..6 --------------
// Normal launch, 256 blocks; hand-rolled grid barrier between levels.
__global__ __launch_bounds__(256)
void tree_chain(const u16* __restrict__ compWt, const u16* __restrict__ compbC,
                const u16* __restrict__ grevWt, const u16* __restrict__ grevbC,
                const u16* __restrict__ decWt,  const u16* __restrict__ decbC,
                const int* __restrict__ x, const int* __restrict__ pos,
                const u16* __restrict__ sembP,
                u16* __restrict__ upB, u16* __restrict__ downB,
                u32* __restrict__ bar)
{
    __shared__ __align__(16) u16 As[16384];   // 4 slots x 8 KB
    __shared__ __align__(16) u16 Bs[16384];
    const int bid = blockIdx.x;

    for (int lvl = 7; lvl >= 0; --lvl) {
        const int M = 32 << lvl;
        const int Mpad = M < 128 ? 128 : M;
        const int ntile = (Mpad >> 7) * 8;           // gx = 8 (N=1024)
        if (bid < ntile) {
            const int bx = bid & 7, by = bid >> 3;
            tile_body_deep<1,1>(As, Bs, compWt, compbC, upB, M, 2112,
                                (1 << lvl) - 1, lvl, x, pos, sembP, upB, downB,
                                by << 7, bx << 7);
        }
        grid_bar(bar, 256);
    }
    if (bid < 8) {
        tile_body_deep<2,1>(As, Bs, grevWt, grevbC, downB, 32, 1088, 0, 0,
                            x, pos, sembP, upB, downB, 0, bid << 7);
    }
    grid_bar(bar, 256);
    for (int lvl = 0; lvl <= 6; ++lvl) {
        const int M = 32 << lvl;
        const int Mpad = M < 128 ? 128 : M;
        const int ntile = (Mpad >> 7) * 16;          // gx = 16 (N=2048)
        if (bid < ntile) {
            const int bx = bid & 15, by = bid >> 4;
            tile_body_deep<3,2>(As, Bs, decWt, decbC, downB, M, 2176,
                                (1 << lvl) - 1, lvl, x, pos, sembP, upB, downB,
                                by << 7, bx << 7);
        }
        if (lvl < 6) grid_bar(bar, 256);
    }
}

// ---------------- classifier: out[b,n,c] = tanh([down|up] . clfW[:,c] + clfb[c]) ----
__global__ __launch_bounds__(256)
void classifier_kernel(const u16* __restrict__ down, const u16* __restrict__ up,
                       const u16* __restrict__ clfW, const u16* __restrict__ clfb,
                       void* __restrict__ outp, const u32* __restrict__ wembU)
{
    __shared__ float wls[3][2048];
    const int isf32 = detect_local(wembU);
    const int tid = threadIdx.x;
    for (int idx = tid; idx < 6144; idx += 256) {
        const int c = idx >> 11, k = idx & 2047;
        wls[c][k] = b2f(clfW[k*3 + c]);
    }
    __syncthreads();
    const int wave = tid >> 6, lane = tid & 63;
    const float b0 = b2f(clfb[0]), b1 = b2f(clfb[1]), b2v = b2f(clfb[2]);
    const int base = blockIdx.x * 32;
    for (int rr = 0; rr < 8; ++rr) {
        const int row = base + rr*4 + wave;     // row = b*NB + node
        const u32* dn = (const u32*)(down + ((size_t)row << 10));
        const u32* un = (const u32*)(up   + ((size_t)row << 10));
        float a0 = 0.f, a1 = 0.f, a2 = 0.f;
        #pragma unroll
        for (int t = 0; t < 8; ++t) {
            const int j = t*64 + lane;
            const u32 dp = dn[j], uu = un[j];
            const int k = j*2;
            const float d0 = __uint_as_float(dp << 16);
            const float d1 = __uint_as_float(dp & 0xffff0000u);
            const float u0 = __uint_as_float(uu << 16);
            const float u1 = __uint_as_float(uu & 0xffff0000u);
            a0 += d0*wls[0][k] + d1*wls[0][k+1] + u0*wls[0][1024+k] + u1*wls[0][1025+k];
            a1 += d0*wls[1][k] + d1*wls[1][k+1] + u0*wls[1][1024+k] + u1*wls[1][1025+k];
            a2 += d0*wls[2][k] + d1*wls[2][k+1] + u0*wls[2][1024+k] + u1*wls[2][1025+k];
        }
        #pragma unroll
        for (int off = 32; off; off >>= 1) {
            a0 += __shfl_down(a0, off);
            a1 += __shfl_down(a1, off);
            a2 += __shfl_down(a2, off);
        }
        if (lane == 0) {
            const float v0 = fast_tanh(a0 + b0);
            const float v1 = fast_tanh(a1 + b1);
            const float v2 = fast_tanh(a2 + b2v);
            if (isf32) {
                float* o = (float*)outp + (size_t)row * 3;
                o[0] = v0; o[1] = v1; o[2] = v2;
            } else {
                u16* o = (u16*)outp + (size_t)row * 3;
                o[0] = f2b(v0); o[1] = f2b(v1); o[2] = f2b(v2);
            }
        }
    }
}

extern "C" void kernel_launch(void* const* d_in, const int* in_sizes, int n_in,
                              void* d_out, int out_size, void* d_ws, size_t ws_size,
                              hipStream_t stream)
{
    (void)in_sizes; (void)n_in; (void)out_size; (void)ws_size;
    const int* x    = (const int*)d_in[0];
    const int* cue  = (const int*)d_in[2];
    const int* pos  = (const int*)d_in[4];
    const void* wemb  = d_in[6];
    const void* semb  = d_in[7];
    const void* leafW = d_in[8];
    const void* leafb = d_in[9];
    const void* compW = d_in[10];
    const void* compb = d_in[11];
    const void* grevW = d_in[12];
    const void* grevb = d_in[13];
    const void* decW  = d_in[14];
    const void* decb  = d_in[15];
    const void* clfW  = d_in[16];
    const void* clfb  = d_in[17];

    char* ws = (char*)d_ws;
    u16* up_buf   = (u16*)(ws + 0);            // 67043328
    u16* down_buf = (u16*)(ws + 67043328);     // 67043328
    u16* ctx      = (u16*)(ws + 134086656);    // 35651584 (leaf only)
    u16* leafWt   = (u16*)(ws + 169738240);    // 1024x1088
    u16* compWt   = (u16*)(ws + 171966464);    // 1024x2112
    u16* grevWt   = (u16*)(ws + 176291840);    // 1024x1088
    u16* decWt    = (u16*)(ws + 178520064);    // 2048x2176
    u16* sembP    = (u16*)(ws + 187432960);    // 128x64
    u16* leafbC   = (u16*)(ws + 187449344);
    u16* compbC   = (u16*)(ws + 187451392);
    u16* grevbC   = (u16*)(ws + 187453440);
    u16* decbC    = (u16*)(ws + 187455488);
    u16* clfbC    = (u16*)(ws + 187459584);
    u16* clfWC    = (u16*)(ws + 187459600);
    u32* barBuf   = (u32*)(ws + 187473920);    // grid barrier (cnt, gen)

    preprocess<<<8717, 256, 0, stream>>>((const u32*)wemb,
        semb, leafb, compb, grevb, decb, clfb, clfW,
        leafW, compW, grevW, decW,
        sembP, leafbC, compbC, grevbC, decbC, clfbC, clfWC,
        leafWt, compWt, grevWt, decWt, barBuf);

    // leaves -> up[511..1022]
    leaf_gather<<<16384, 256, 0, stream>>>(x, cue, pos, wemb, sembP, ctx);
    gemm_fused<0,0><<<dim3(8, 128), 256, 0, stream>>>(leafWt, leafbC, up_buf,
        16384, 1088, 511, 9, 0, ctx, x, pos, sembP, up_buf, down_buf);
    // up lvl 8 (big, 512 tiles)
    gemm_fused<1,1><<<dim3(8, 64), 256, 0, stream>>>(compWt, compbC, up_buf,
        8192, 2112, 255, 8, 0, nullptr, x, pos, sembP, up_buf, down_buf);

    // fused chain: up 7..0 -> root -> down 0..6 (one dispatch, manual grid barrier)
    tree_chain<<<256, 256, 0, stream>>>(compWt, compbC, grevWt, grevbC,
                                        decWt, decbC, x, pos, sembP,
                                        up_buf, down_buf, barBuf);

    // down lvl 7, 8 (big)
    gemm_fused<3,2><<<dim3(16, 32), 256, 0, stream>>>(decWt, decbC, down_buf,
        4096, 2176, 127, 7, 0, nullptr, x, pos, sembP, up_buf, down_buf);
    gemm_fused<3,2><<<dim3(16, 64), 256, 0, stream>>>(decWt, decbC, down_buf,
        8192, 2176, 255, 8, 1, nullptr, x, pos, sembP, up_buf, down_buf);

    // classifier
    classifier_kernel<<<1023, 256, 0, stream>>>(down_buf, up_buf, clfWC, clfbC,
                                                d_out, (const u32*)wemb);
}

// Round 3
// 1124.011 us; speedup vs baseline: 1.6892x; 1.4529x over previous
//
#include <hip/hip_runtime.h>

typedef unsigned short u16;
typedef unsigned int   u32;

typedef __bf16 bf16x8 __attribute__((ext_vector_type(8)));
typedef float  f32x4  __attribute__((ext_vector_type(4)));
typedef u32    u32x4  __attribute__((ext_vector_type(4)));

#define NB 1023   // nodes per tree
#define HH 1024   // hidden

__device__ __forceinline__ float b2f(u16 x) { return __uint_as_float(((u32)x) << 16); }
__device__ __forceinline__ u16 f2b(float f) {
    u32 u = __float_as_uint(f);
    u += 0x7fffu + ((u >> 16) & 1u);   // RTNE
    return (u16)(u >> 16);
}
__device__ __forceinline__ float fast_tanh(float x) {
    float cx = fminf(fmaxf(x, -12.f), 12.f);
    float e = __expf(2.f * cx);
    return __fdividef(e - 1.f, e + 1.f);
}
// plain (L2-cached) global->LDS DMA
__device__ __forceinline__ void async_copy16(const void* gptr, void* lptr) {
    __builtin_amdgcn_global_load_lds((__attribute__((address_space(1))) void*)gptr,
                                     (__attribute__((address_space(3))) void*)lptr,
                                     16, 0, 0);
}
// device-coherent (sc1: bypass L2, read at L3) global->LDS DMA — for buffers
// written by other XCDs within the same dispatch.
__device__ __forceinline__ void async_copy16_c(const void* gptr, void* lptr) {
    __builtin_amdgcn_global_load_lds((__attribute__((address_space(1))) void*)gptr,
                                     (__attribute__((address_space(3))) void*)lptr,
                                     16, 0, 16);
}
// device-coherent u16 store (write-through to L3): visible to other XCDs
// after the storing wave drains vmcnt — no cache maintenance needed.
__device__ __forceinline__ void store_u16_dev(u16* p, u16 v) {
    asm volatile("global_store_short %0, %1, off sc0 sc1"
                 :: "v"((unsigned long long)(size_t)p), "v"((u32)v) : "memory");
}
__device__ __forceinline__ u16 loadAsBf16(const void* p, size_t idx, int isf32) {
    if (isf32) return f2b(((const float*)p)[idx]);
    return ((const u16*)p)[idx];
}

// per-block dtype detection: f32 mantissa low-halves have random exponents.
__device__ __forceinline__ int detect_local(const u32* __restrict__ w) {
    __shared__ int cnt;
    const int tid = threadIdx.x;
    if (tid == 0) cnt = 0;
    __syncthreads();
    u32 v = w[tid & 255];
    u32 lo = v & 0xFFFFu;
    u32 e = (lo >> 7) & 0xFFu;
    if ((lo != 0u) && (e < 60u || e > 140u)) atomicAdd(&cnt, 1);
    __syncthreads();
    return cnt >= 64;
}

// ---------------- fence-free grid barrier -----------------------------------------
// Data written with sc1 stores is at L3 once the writer's vmcnt drains (the
// __syncthreads drain does this per wave). Arrive: one fetch_add. Release: the
// last arriver writes a per-block flag line (64 B apart -> no poll contention).
// Readers poll their own line with sc1 loads.
__device__ __forceinline__ void grid_bar(u32* bar, u32* flags, u32 gen, int nb) {
    __syncthreads();   // implicit vmcnt(0) per wave: all sc1 stores at L3
    if (threadIdx.x == 0) {
        asm volatile("s_waitcnt vmcnt(0) lgkmcnt(0)" ::: "memory");
        u32 v = __hip_atomic_fetch_add(&bar[0], 1u, __ATOMIC_RELAXED, __HIP_MEMORY_SCOPE_AGENT);
        if (v == (u32)nb - 1u) {
            __hip_atomic_store(&bar[0], 0u, __ATOMIC_RELAXED, __HIP_MEMORY_SCOPE_AGENT);
            asm volatile("s_waitcnt vmcnt(0)" ::: "memory");   // reset lands before flags
            for (int i = 0; i < nb; ++i)
                __hip_atomic_store(&flags[i * 16], gen, __ATOMIC_RELAXED, __HIP_MEMORY_SCOPE_AGENT);
        } else {
            while (__hip_atomic_load(&flags[blockIdx.x * 16], __ATOMIC_RELAXED,
                                     __HIP_MEMORY_SCOPE_AGENT) < gen) {
                __builtin_amdgcn_s_sleep(8);
            }
        }
    }
    __syncthreads();
}

// ---------------- unified preprocessing ----------------
__device__ void conv_range(const void* __restrict__ src, u16* __restrict__ dst,
                           int n, int tbase, int isf32) {
    const int i = ((int)blockIdx.x - tbase) * 256 + threadIdx.x;
    if (i < n) dst[i] = loadAsBf16(src, i, isf32);
}

__device__ void transpose_tile(const void* __restrict__ W, u16* __restrict__ Wt,
                               int Nw, int Kpad, int bx, int by, int isf32,
                               int ps0, int ps1, int ps2, int ps3,
                               int os0, int os1, int os2, int os3,
                               int ln0, int ln1, int ln2, int ln3)
{
    __shared__ u16 tile[32][33];
    const int tid = threadIdx.x;
    const int tx = tid & 31, ty = tid >> 5;
    #pragma unroll
    for (int i = 0; i < 4; ++i) {
        const int kp = by*32 + ty + i*8;
        const int n = bx*32 + tx;
        int ko = -1;
        if      (kp >= ps0 && kp < ps0 + ln0) ko = os0 + (kp - ps0);
        else if (kp >= ps1 && kp < ps1 + ln1) ko = os1 + (kp - ps1);
        else if (kp >= ps2 && kp < ps2 + ln2) ko = os2 + (kp - ps2);
        else if (kp >= ps3 && kp < ps3 + ln3) ko = os3 + (kp - ps3);
        u16 v = 0;
        if (ko >= 0) v = loadAsBf16(W, (size_t)ko * Nw + n, isf32);
        tile[ty + i*8][tx] = v;
    }
    __syncthreads();
    #pragma unroll
    for (int i = 0; i < 4; ++i) {
        const int n = bx*32 + ty + i*8;
        const int kp = by*32 + tx;
        Wt[(size_t)n * Kpad + kp] = tile[tx][ty + i*8];
    }
}

__global__ __launch_bounds__(256)
void preprocess(const u32* __restrict__ wembU,
                const void* __restrict__ semb,  const void* __restrict__ leafb,
                const void* __restrict__ compb, const void* __restrict__ grevb,
                const void* __restrict__ decb,  const void* __restrict__ clfb,
                const void* __restrict__ clfW,
                const void* __restrict__ leafW, const void* __restrict__ compW,
                const void* __restrict__ grevW, const void* __restrict__ decW,
                u16* __restrict__ sembP,  u16* __restrict__ leafbC,
                u16* __restrict__ compbC, u16* __restrict__ grevbC,
                u16* __restrict__ decbC,  u16* __restrict__ clfbC,
                u16* __restrict__ clfWC,
                u16* __restrict__ leafWt, u16* __restrict__ compWt,
                u16* __restrict__ grevWt, u16* __restrict__ decWt,
                u32* __restrict__ bar, u32* __restrict__ flags)
{
    const int isf32 = detect_local(wembU);
    const int bid = blockIdx.x;
    if (bid == 0) {
        if (threadIdx.x == 0) { bar[0] = 0; bar[1] = 0; }
        flags[threadIdx.x * 16] = 0;           // 256 poll lines
    }
    if (bid < 32) {                       // sembP: 128 rows, 50 -> 64 pad
        const int i = bid * 256 + threadIdx.x;   // 8192
        const int s = i >> 6, c = i & 63;
        sembP[i] = (c < 50) ? loadAsBf16(semb, s * 50 + c, isf32) : (u16)0;
    } else if (bid < 36)  conv_range(leafb, leafbC, 1024, 32, isf32);
    else if (bid < 40)  conv_range(compb, compbC, 1024, 36, isf32);
    else if (bid < 44)  conv_range(grevb, grevbC, 1024, 40, isf32);
    else if (bid < 52)  conv_range(decb,  decbC,  2048, 44, isf32);
    else if (bid < 53)  conv_range(clfb,  clfbC,  3,    52, isf32);
    else if (bid < 77)  conv_range(clfW,  clfWC,  6144, 53, isf32);
    else if (bid < 1165) {                // leafWt 32x34
        const int t = bid - 77;
        transpose_tile(leafW, leafWt, 1024, 1088, t & 31, t >> 5, isf32,
                       0,-1,-1,-1,  0,0,0,0,  1077,0,0,0);
    } else if (bid < 3277) {              // compWt 32x66
        const int t = bid - 1165;
        transpose_tile(compW, compWt, 1024, 2112, t & 31, t >> 5, isf32,
                       0,64,1088,-1,  0,50,1074,0,  50,1024,1024,0);
    } else if (bid < 4365) {              // grevWt 32x34
        const int t = bid - 3277;
        transpose_tile(grevW, grevWt, 1024, 1088, t & 31, t >> 5, isf32,
                       0,1024,-1,-1,  0,1024,0,0,  1024,50,0,0);
    } else {                              // decWt 64x68
        const int t = bid - 4365;
        transpose_tile(decW, decWt, 2048, 2176, t & 63, t >> 6, isf32,
                       0,64,128,1152,  0,50,100,1124,  50,50,1024,1024);
    }
}

// ---------------- leaf ctx (Kpad=1088): [word(1024) | onehot(3) | syn(pos)(50) | 0(11)]
__global__ __launch_bounds__(256)
void leaf_gather(const int* __restrict__ x, const int* __restrict__ cue,
                 const int* __restrict__ pos, const void* __restrict__ wemb,
                 const u16* __restrict__ sembP, u16* __restrict__ ctx)
{
    const int isf32 = detect_local((const u32*)wemb);
    const int m = blockIdx.x;           // 0..16383
    const int b = m >> 9, i = m & 511;
    const int node = 511 + i;
    const int s  = x[b*NB + node];
    const int cv = cue[b*NB + node];
    const int p  = pos[b*512 + i];
    u16* row = ctx + (size_t)m * 1088;
    u32* row32 = (u32*)row;
    const u16* sr = sembP + p * 64;
    const int tid = threadIdx.x;
    if (isf32) {
        const float2* wrf = ((const float2*)wemb) + (size_t)s * 512;
        for (int c = tid; c < 512; c += 256) {
            float2 t = wrf[c];
            row32[c] = (u32)f2b(t.x) | ((u32)f2b(t.y) << 16);
        }
    } else {
        const u32* wr = ((const u32*)wemb) + (size_t)s * 512;
        for (int c = tid; c < 512; c += 256) row32[c] = wr[c];
    }
    if (tid < 64) {
        const int c = tid;              // elem 1024+c
        u16 v;
        if (c < 3)       v = (c == cv) ? (u16)0x3F80 : (u16)0;
        else if (c < 53) v = sr[c - 3];
        else             v = 0;
        row[1024 + c] = v;
    }
}

// ---------------- fused gather+GEMM tile body (shallow, for big multi-block levels)
// AKIND 0: A = actx rows (leaf).             Kpad=1088
// AKIND 1: up level:   [semb(s)|up_l|up_r]   Kpad=2112 (64+1024+1024)
// AKIND 2: root:       [up0|semb(s)]         Kpad=1088 (1024+64)
// AKIND 3: down level: [sL|sR|down_n|up_n]   Kpad=2176 (64+64+1024+1024)
// MODE 0: store raw; 1: tanh; 2: tanh + child split (N=2048)
template<int AKIND, int MODE>
__device__ __forceinline__ void tile_body(
    u16* __restrict__ As, u16* __restrict__ Bs,
    const u16* __restrict__ Bt, const u16* __restrict__ bias,
    u16* __restrict__ dst, int M, int Kpad, int nodeBase, int lognn,
    int leafLvl,
    const u16* __restrict__ actx,
    const int* __restrict__ x, const int* __restrict__ pos,
    const u16* __restrict__ sembP,
    const u16* __restrict__ upB, const u16* __restrict__ downB,
    int bm, int bn)
{
    const int tid  = threadIdx.x;
    const int wave = tid >> 6;
    const int lane = tid & 63;
    const int wm = (wave & 1) << 6;
    const int wn = (wave >> 1) << 6;
    const int quad = lane >> 4;
    const int l16  = lane & 15;
    const int srow = lane >> 2;
    const int scol = (lane & 3) << 3;
    const int mask = (1 << lognn) - 1;

    const u16* p0[2]; const u16* p1[2]; const u16* p2[2]; const u16* p3[2];
    #pragma unroll
    for (int h = 0; h < 2; ++h) {
        const int mrow = bm + wave*16 + srow + h*64;
        const int mr = (mrow < M) ? mrow : 0;
        if (AKIND == 0) {
            p0[h] = actx + (size_t)mr * Kpad + scol;
        } else if (AKIND == 1) {
            const int b_ = mr >> lognn, ii = mr & mask;
            const int node = nodeBase + ii;
            const int s = x[b_*NB + node];
            p0[h] = sembP + s*64 + scol;
            p1[h] = upB + (((size_t)(b_*NB + 2*node + 1)) << 10) + scol;
            p2[h] = upB + (((size_t)(b_*NB + 2*node + 2)) << 10) + scol;
        } else if (AKIND == 2) {
            p0[h] = upB + (((size_t)(mr*NB)) << 10) + scol;
            p1[h] = sembP + x[mr*NB]*64 + scol;
        } else {
            const int b_ = mr >> lognn, ii = mr & mask;
            const int node = nodeBase + ii;
            const int l = 2*node + 1, r = l + 1;
            int sli, sri;
            if (leafLvl) { sli = pos[b_*512 + (l-511)]; sri = pos[b_*512 + (r-511)]; }
            else         { sli = x[b_*NB + l]; sri = x[b_*NB + r]; }
            p0[h] = sembP + sli*64 + scol;
            p1[h] = sembP + sri*64 + scol;
            p2[h] = downB + (((size_t)(b_*NB + node)) << 10) + scol;
            p3[h] = upB   + (((size_t)(b_*NB + node)) << 10) + scol;
        }
    }

    const u16* gB0 = Bt + (size_t)(bn + wave*16 + srow) * Kpad + scol;
    const u16* gB1 = gB0 + (size_t)64 * Kpad;
    u16* lA0 = As + wave * 512;
    u16* lA1 = As + (wave + 4) * 512;
    u16* lB0 = Bs + wave * 512;
    u16* lB1 = Bs + (wave + 4) * 512;

    const u16* pa[4]; const u16* pb[4];
    #pragma unroll
    for (int i = 0; i < 4; ++i) pa[i] = As + (wm + i*16 + l16) * 32 + quad*8;
    #pragma unroll
    for (int j = 0; j < 4; ++j) pb[j] = Bs + (wn + j*16 + l16) * 32 + quad*8;

    f32x4 zero4 = {0.f, 0.f, 0.f, 0.f};
    f32x4 acc[4][4];
    #pragma unroll
    for (int i = 0; i < 4; ++i)
        #pragma unroll
        for (int j = 0; j < 4; ++j) acc[i][j] = zero4;

    auto srcA = [&](int h, int k0) -> const u16* {
        if (AKIND == 0) return p0[h] + k0;
        if (AKIND == 1) return (k0 < 64) ? p0[h] + k0
                             : (k0 < 1088) ? p1[h] + (k0 - 64)
                             : p2[h] + (k0 - 1088);
        if (AKIND == 2) return (k0 < 1024) ? p0[h] + k0 : p1[h] + (k0 - 1024);
        return (k0 < 64)   ? p0[h] + k0
             : (k0 < 128)  ? p1[h] + (k0 - 64)
             : (k0 < 1152) ? p2[h] + (k0 - 128)
             : p3[h] + (k0 - 1152);
    };
    auto stage = [&](int c) {
        const int off = (c & 1) << 12;
        const int k0  = c << 5;
        async_copy16(srcA(0, k0), lA0 + off);
        async_copy16(srcA(1, k0), lA1 + off);
        async_copy16(gB0 + k0,    lB0 + off);
        async_copy16(gB1 + k0,    lB1 + off);
    };

    const int NT = Kpad >> 5;
    stage(0);
    __syncthreads();
    for (int c = 0; c < NT; ++c) {
        if (c + 1 < NT) stage(c + 1);
        const int off = (c & 1) << 12;
        bf16x8 a[4], b[4];
        #pragma unroll
        for (int i = 0; i < 4; ++i) a[i] = *(const bf16x8*)(pa[i] + off);
        #pragma unroll
        for (int j = 0; j < 4; ++j) b[j] = *(const bf16x8*)(pb[j] + off);
        #pragma unroll
        for (int i = 0; i < 4; ++i)
            #pragma unroll
            for (int j = 0; j < 4; ++j)
                acc[i][j] = __builtin_amdgcn_mfma_f32_16x16x32_bf16(a[i], b[j], acc[i][j], 0, 0, 0);
        __syncthreads();
    }

    #pragma unroll
    for (int i = 0; i < 4; ++i) {
        #pragma unroll
        for (int j = 0; j < 4; ++j) {
            const int gn = bn + wn + j*16 + l16;
            const float bv = b2f(bias[gn]);
            #pragma unroll
            for (int r = 0; r < 4; ++r) {
                const int gm = bm + wm + i*16 + quad*4 + r;
                if (gm < M) {
                    float v = acc[i][j][r] + bv;
                    if (MODE != 0) v = fast_tanh(v);
                    const int b_ = gm >> lognn;
                    const int ii = gm & mask;
                    const int node = nodeBase + ii;
                    size_t addr;
                    if (MODE == 2) {
                        const int child = 2*node + 1 + (gn >> 10);
                        addr = (((size_t)(b_*NB + child)) << 10) + (gn & 1023);
                    } else {
                        addr = (((size_t)(b_*NB + node)) << 10) + gn;
                    }
                    dst[addr] = f2b(v);
                }
            }
        }
    }
}

// ---------------- deep-pipelined tile body for the chain (1 block/CU) -------------
// KPAD is a template param: the chunk loop FULLY UNROLLS so every LDS offset is a
// compile-time constant, the ds_reads are inline asm with immediate offsets, and
// the counted s_waitcnt vmcnt(8) actually holds (the compiler cannot insert a
// conservative vmcnt(0) for DMA/read aliasing). Depth-3 prefetch, 4 LDS slots,
// ONE s_barrier per chunk. Outputs stored sc1 (L3-coherent); chain-internal A rows
// staged with sc1 DMAs.
template<int AKIND, int MODE, int KPAD>
__device__ __forceinline__ void tile_body_deep(
    u16* __restrict__ As, u16* __restrict__ Bs,
    const u16* __restrict__ Bt, const u16* __restrict__ bias,
    u16* __restrict__ dst, int M, int nodeBase, int lognn,
    const int* __restrict__ x,
    const u16* __restrict__ sembP,
    const u16* __restrict__ upB, const u16* __restrict__ downB,
    int bm, int bn)
{
    const int tid  = threadIdx.x;
    const int wave = tid >> 6;
    const int lane = tid & 63;
    const int wm = (wave & 1) << 6;
    const int wn = (wave >> 1) << 6;
    const int quad = lane >> 4;
    const int l16  = lane & 15;
    const int srow = lane >> 2;
    const int scol = (lane & 3) << 3;
    const int mask = (1 << lognn) - 1;

    const u16* p0[2]; const u16* p1[2]; const u16* p2[2]; const u16* p3[2];
    #pragma unroll
    for (int h = 0; h < 2; ++h) {
        const int mrow = bm + wave*16 + srow + h*64;
        const int mr = (mrow < M) ? mrow : 0;
        if (AKIND == 1) {
            const int b_ = mr >> lognn, ii = mr & mask;
            const int node = nodeBase + ii;
            const int s = x[b_*NB + node];
            p0[h] = sembP + s*64 + scol;
            p1[h] = upB + (((size_t)(b_*NB + 2*node + 1)) << 10) + scol;
            p2[h] = upB + (((size_t)(b_*NB + 2*node + 2)) << 10) + scol;
        } else if (AKIND == 2) {
            p0[h] = upB + (((size_t)(mr*NB)) << 10) + scol;
            p1[h] = sembP + x[mr*NB]*64 + scol;
        } else {
            const int b_ = mr >> lognn, ii = mr & mask;
            const int node = nodeBase + ii;
            const int l = 2*node + 1, r = l + 1;
            const int sli = x[b_*NB + l], sri = x[b_*NB + r];
            p0[h] = sembP + sli*64 + scol;
            p1[h] = sembP + sri*64 + scol;
            p2[h] = downB + (((size_t)(b_*NB + node)) << 10) + scol;
            p3[h] = upB   + (((size_t)(b_*NB + node)) << 10) + scol;
        }
    }

    const u16* gB0 = Bt + (size_t)(bn + wave*16 + srow) * KPAD + scol;
    const u16* gB1 = gB0 + (size_t)64 * KPAD;
    u16* lA0 = As + wave * 512;
    u16* lA1 = As + (wave + 4) * 512;
    u16* lB0 = Bs + wave * 512;
    u16* lB1 = Bs + (wave + 4) * 512;

    // 32-bit LDS byte addresses for inline-asm ds_read_b128
    const u32 a_base = (u32)(size_t)(__attribute__((address_space(3))) const u16*)As;
    const u32 b_base = (u32)(size_t)(__attribute__((address_space(3))) const u16*)Bs;
    const u32 a_rd0 = a_base + (u32)((wm + l16) * 64 + quad * 16);
    const u32 b_rd0 = b_base + (u32)((wn + l16) * 64 + quad * 16);

    f32x4 zero4 = {0.f, 0.f, 0.f, 0.f};
    f32x4 acc[4][4];
    #pragma unroll
    for (int i = 0; i < 4; ++i)
        #pragma unroll
        for (int j = 0; j < 4; ++j) acc[i][j] = zero4;

    // A-row staging with per-segment coherence (sc1 for chain-written buffers)
    auto stageA = [&](int h, int c, u16* ldst) {
        const int k0 = c << 5;
        if (AKIND == 1) {
            if (k0 < 64)        async_copy16  (p0[h] + k0,          ldst);
            else if (k0 < 1088) async_copy16_c(p1[h] + (k0 - 64),   ldst);
            else                async_copy16_c(p2[h] + (k0 - 1088), ldst);
        } else if (AKIND == 2) {
            if (k0 < 1024)      async_copy16_c(p0[h] + k0,          ldst);
            else                async_copy16  (p1[h] + (k0 - 1024), ldst);
        } else {
            if (k0 < 64)        async_copy16  (p0[h] + k0,          ldst);
            else if (k0 < 128)  async_copy16  (p1[h] + (k0 - 64),   ldst);
            else if (k0 < 1152) async_copy16_c(p2[h] + (k0 - 128),  ldst);
            else                async_copy16_c(p3[h] + (k0 - 1152), ldst);
        }
    };
    auto stage = [&](int c) {
        const int off = (c & 3) << 12;     // 4 slots x 4096 u16 (8 KB)
        stageA(0, c, lA0 + off);
        stageA(1, c, lA1 + off);
        async_copy16(gB0 + (c << 5), lB0 + off);
        async_copy16(gB1 + (c << 5), lB1 + off);
    };

    constexpr int NT = KPAD >> 5;
    stage(0); stage(1); stage(2);          // depth-3: 12 DMAs in flight per wave

#define DSR(dst_, addr_, lit_) \
    asm volatile("ds_read_b128 %0, %1 offset:" #lit_ : "=v"(dst_) : "v"(addr_))

    #pragma unroll
    for (int c = 0; c < NT; ++c) {
        if (c + 2 < NT)      asm volatile("s_waitcnt vmcnt(8)" ::: "memory");
        else if (c + 1 < NT) asm volatile("s_waitcnt vmcnt(4)" ::: "memory");
        else                 asm volatile("s_waitcnt vmcnt(0)" ::: "memory");
        asm volatile("s_barrier" ::: "memory");    // all waves' chunk-c DMAs landed
        if (c + 3 < NT) stage(c + 3);              // overwrites slot staged this iter-4: safe
        const u32 ar = a_rd0 + (u32)((c & 3) << 13);
        const u32 br = b_rd0 + (u32)((c & 3) << 13);
        u32x4 ra0, ra1, ra2, ra3, rb0, rb1, rb2, rb3;
        DSR(ra0, ar, 0);  DSR(ra1, ar, 1024); DSR(ra2, ar, 2048); DSR(ra3, ar, 3072);
        DSR(rb0, br, 0);  DSR(rb1, br, 1024); DSR(rb2, br, 2048); DSR(rb3, br, 3072);
        asm volatile("s_waitcnt lgkmcnt(0)" ::: "memory");
        __builtin_amdgcn_sched_barrier(0);
        bf16x8 a[4], b[4];
        a[0] = __builtin_bit_cast(bf16x8, ra0); a[1] = __builtin_bit_cast(bf16x8, ra1);
        a[2] = __builtin_bit_cast(bf16x8, ra2); a[3] = __builtin_bit_cast(bf16x8, ra3);
        b[0] = __builtin_bit_cast(bf16x8, rb0); b[1] = __builtin_bit_cast(bf16x8, rb1);
        b[2] = __builtin_bit_cast(bf16x8, rb2); b[3] = __builtin_bit_cast(bf16x8, rb3);
        #pragma unroll
        for (int i = 0; i < 4; ++i)
            #pragma unroll
            for (int j = 0; j < 4; ++j)
                acc[i][j] = __builtin_amdgcn_mfma_f32_16x16x32_bf16(a[i], b[j], acc[i][j], 0, 0, 0);
    }
#undef DSR

    #pragma unroll
    for (int i = 0; i < 4; ++i) {
        #pragma unroll
        for (int j = 0; j < 4; ++j) {
            const int gn = bn + wn + j*16 + l16;
            const float bv = b2f(bias[gn]);
            #pragma unroll
            for (int r = 0; r < 4; ++r) {
                const int gm = bm + wm + i*16 + quad*4 + r;
                if (gm < M) {
                    float v = acc[i][j][r] + bv;
                    v = fast_tanh(v);
                    const int b_ = gm >> lognn;
                    const int ii = gm & mask;
                    const int node = nodeBase + ii;
                    size_t addr;
                    if (MODE == 2) {
                        const int child = 2*node + 1 + (gn >> 10);
                        addr = (((size_t)(b_*NB + child)) << 10) + (gn & 1023);
                    } else {
                        addr = (((size_t)(b_*NB + node)) << 10) + gn;
                    }
                    store_u16_dev(&dst[addr], f2b(v));   // sc1: visible cross-XCD
                }
            }
        }
    }
}

template<int AKIND, int MODE>
__global__ __launch_bounds__(256)
void gemm_fused(const u16* __restrict__ Bt, const u16* __restrict__ bias,
                u16* __restrict__ dst, int M, int Kpad, int nodeBase, int lognn,
                int leafLvl,
                const u16* __restrict__ actx,
                const int* __restrict__ x, const int* __restrict__ pos,
                const u16* __restrict__ sembP,
                const u16* __restrict__ upB, const u16* __restrict__ downB)
{
    __shared__ __align__(16) u16 As[8192];
    __shared__ __align__(16) u16 Bs[8192];
    // bijective XCD swizzle (m204)
    const int gx  = gridDim.x;
    const int nwg = gx * gridDim.y;
    int bid = blockIdx.y * gx + blockIdx.x;
    const int q = nwg >> 3, r = nwg & 7;
    const int xcd = bid & 7, lid = bid >> 3;
    bid = (xcd < r ? xcd * (q + 1) : r * (q + 1) + (xcd - r) * q) + lid;
    const int bx = bid % gx, by = bid / gx;
    tile_body<AKIND, MODE>(As, Bs, Bt, bias, dst, M, Kpad, nodeBase, lognn,
                           leafLvl, actx, x, pos, sembP, upB, downB,
                           by << 7, bx << 7);
}

// ---------------- chained small levels: up 7..0 -> root -> down 0..6 --------------
__global__ __launch_bounds__(256)
void tree_chain(const u16* __restrict__ compWt, const u16* __restrict__ compbC,
                const u16* __restrict__ grevWt, const u16* __restrict__ grevbC,
                const u16* __restrict__ decWt,  const u16* __restrict__ decbC,
                const int* __restrict__ x, const int* __restrict__ pos,
                const u16* __restrict__ sembP,
                u16* __restrict__ upB, u16* __restrict__ downB,
                u32* __restrict__ bar, u32* __restrict__ flags)
{
    __shared__ __align__(16) u16 As[16384];   // 4 slots x 8 KB
    __shared__ __align__(16) u16 Bs[16384];
    const int bid = blockIdx.x;
    u32 gen = 0;

    for (int lvl = 7; lvl >= 0; --lvl) {
        const int M = 32 << lvl;
        const int Mpad = M < 128 ? 128 : M;
        const int ntile = (Mpad >> 7) * 8;           // gx = 8 (N=1024)
        if (bid < ntile) {
            const int bx = bid & 7, by = bid >> 3;
            tile_body_deep<1,1,2112>(As, Bs, compWt, compbC, upB, M,
                                     (1 << lvl) - 1, lvl, x, sembP, upB, downB,
                                     by << 7, bx << 7);
        }
        grid_bar(bar, flags, ++gen, 256);
    }
    if (bid < 8) {
        tile_body_deep<2,1,1088>(As, Bs, grevWt, grevbC, downB, 32, 0, 0,
                                 x, sembP, upB, downB, 0, bid << 7);
    }
    grid_bar(bar, flags, ++gen, 256);
    for (int lvl = 0; lvl <= 6; ++lvl) {
        const int M = 32 << lvl;
        const int Mpad = M < 128 ? 128 : M;
        const int ntile = (Mpad >> 7) * 16;          // gx = 16 (N=2048)
        if (bid < ntile) {
            const int bx = bid & 15, by = bid >> 4;
            tile_body_deep<3,2,2176>(As, Bs, decWt, decbC, downB, M,
                                     (1 << lvl) - 1, lvl, x, sembP, upB, downB,
                                     by << 7, bx << 7);
        }
        if (lvl < 6) grid_bar(bar, flags, ++gen, 256);
    }
}

// ---------------- classifier: out[b,n,c] = tanh([down|up] . clfW[:,c] + clfb[c]) ----
__global__ __launch_bounds__(256)
void classifier_kernel(const u16* __restrict__ down, const u16* __restrict__ up,
                       const u16* __restrict__ clfW, const u16* __restrict__ clfb,
                       void* __restrict__ outp, const u32* __restrict__ wembU)
{
    __shared__ float wls[3][2048];
    const int isf32 = detect_local(wembU);
    const int tid = threadIdx.x;
    for (int idx = tid; idx < 6144; idx += 256) {
        const int c = idx >> 11, k = idx & 2047;
        wls[c][k] = b2f(clfW[k*3 + c]);
    }
    __syncthreads();
    const int wave = tid >> 6, lane = tid & 63;
    const float b0 = b2f(clfb[0]), b1 = b2f(clfb[1]), b2v = b2f(clfb[2]);
    const int base = blockIdx.x * 32;
    for (int rr = 0; rr < 8; ++rr) {
        const int row = base + rr*4 + wave;     // row = b*NB + node
        const u32* dn = (const u32*)(down + ((size_t)row << 10));
        const u32* un = (const u32*)(up   + ((size_t)row << 10));
        float a0 = 0.f, a1 = 0.f, a2 = 0.f;
        #pragma unroll
        for (int t = 0; t < 8; ++t) {
            const int j = t*64 + lane;
            const u32 dp = dn[j], uu = un[j];
            const int k = j*2;
            const float d0 = __uint_as_float(dp << 16);
            const float d1 = __uint_as_float(dp & 0xffff0000u);
            const float u0 = __uint_as_float(uu << 16);
            const float u1 = __uint_as_float(uu & 0xffff0000u);
            a0 += d0*wls[0][k] + d1*wls[0][k+1] + u0*wls[0][1024+k] + u1*wls[0][1025+k];
            a1 += d0*wls[1][k] + d1*wls[1][k+1] + u0*wls[1][1024+k] + u1*wls[1][1025+k];
            a2 += d0*wls[2][k] + d1*wls[2][k+1] + u0*wls[2][1024+k] + u1*wls[2][1025+k];
        }
        #pragma unroll
        for (int off = 32; off; off >>= 1) {
            a0 += __shfl_down(a0, off);
            a1 += __shfl_down(a1, off);
            a2 += __shfl_down(a2, off);
        }
        if (lane == 0) {
            const float v0 = fast_tanh(a0 + b0);
            const float v1 = fast_tanh(a1 + b1);
            const float v2 = fast_tanh(a2 + b2v);
            if (isf32) {
                float* o = (float*)outp + (size_t)row * 3;
                o[0] = v0; o[1] = v1; o[2] = v2;
            } else {
                u16* o = (u16*)outp + (size_t)row * 3;
                o[0] = f2b(v0); o[1] = f2b(v1); o[2] = f2b(v2);
            }
        }
    }
}

extern "C" void kernel_launch(void* const* d_in, const int* in_sizes, int n_in,
                              void* d_out, int out_size, void* d_ws, size_t ws_size,
                              hipStream_t stream)
{
    (void)in_sizes; (void)n_in; (void)out_size; (void)ws_size;
    const int* x    = (const int*)d_in[0];
    const int* cue  = (const int*)d_in[2];
    const int* pos  = (const int*)d_in[4];
    const void* wemb  = d_in[6];
    const void* semb  = d_in[7];
    const void* leafW = d_in[8];
    const void* leafb = d_in[9];
    const void* compW = d_in[10];
    const void* compb = d_in[11];
    const void* grevW = d_in[12];
    const void* grevb = d_in[13];
    const void* decW  = d_in[14];
    const void* decb  = d_in[15];
    const void* clfW  = d_in[16];
    const void* clfb  = d_in[17];

    char* ws = (char*)d_ws;
    u16* up_buf   = (u16*)(ws + 0);            // 67043328
    u16* down_buf = (u16*)(ws + 67043328);     // 67043328
    u16* ctx      = (u16*)(ws + 134086656);    // 35651584 (leaf only)
    u16* leafWt   = (u16*)(ws + 169738240);    // 1024x1088
    u16* compWt   = (u16*)(ws + 171966464);    // 1024x2112
    u16* grevWt   = (u16*)(ws + 176291840);    // 1024x1088
    u16* decWt    = (u16*)(ws + 178520064);    // 2048x2176
    u16* sembP    = (u16*)(ws + 187432960);    // 128x64
    u16* leafbC   = (u16*)(ws + 187449344);
    u16* compbC   = (u16*)(ws + 187451392);
    u16* grevbC   = (u16*)(ws + 187453440);
    u16* decbC    = (u16*)(ws + 187455488);
    u16* clfbC    = (u16*)(ws + 187459584);
    u16* clfWC    = (u16*)(ws + 187459600);
    u32* barBuf   = (u32*)(ws + 187473920);    // grid barrier (cnt, gen)
    u32* flagsBuf = (u32*)(ws + 187473984);    // 256 poll lines x 64 B

    preprocess<<<8717, 256, 0, stream>>>((const u32*)wemb,
        semb, leafb, compb, grevb, decb, clfb, clfW,
        leafW, compW, grevW, decW,
        sembP, leafbC, compbC, grevbC, decbC, clfbC, clfWC,
        leafWt, compWt, grevWt, decWt, barBuf, flagsBuf);

    // leaves -> up[511..1022]
    leaf_gather<<<16384, 256, 0, stream>>>(x, cue, pos, wemb, sembP, ctx);
    gemm_fused<0,0><<<dim3(8, 128), 256, 0, stream>>>(leafWt, leafbC, up_buf,
        16384, 1088, 511, 9, 0, ctx, x, pos, sembP, up_buf, down_buf);
    // up lvl 8 (big, 512 tiles)
    gemm_fused<1,1><<<dim3(8, 64), 256, 0, stream>>>(compWt, compbC, up_buf,
        8192, 2112, 255, 8, 0, nullptr, x, pos, sembP, up_buf, down_buf);

    // fused chain: up 7..0 -> root -> down 0..6 (one dispatch, manual grid barrier)
    tree_chain<<<256, 256, 0, stream>>>(compWt, compbC, grevWt, grevbC,
                                        decWt, decbC, x, pos, sembP,
                                        up_buf, down_buf, barBuf, flagsBuf);

    // down lvl 7, 8 (big)
    gemm_fused<3,2><<<dim3(16, 32), 256, 0, stream>>>(decWt, decbC, down_buf,
        4096, 2176, 127, 7, 0, nullptr, x, pos, sembP, up_buf, down_buf);
    gemm_fused<3,2><<<dim3(16, 64), 256, 0, stream>>>(decWt, decbC, down_buf,
        8192, 2176, 255, 8, 1, nullptr, x, pos, sembP, up_buf, down_buf);

    // classifier
    classifier_kernel<<<1023, 256, 0, stream>>>(down_buf, up_buf, clfWC, clfbC,
                                                d_out, (const u32*)wemb);
}